// Round 4
// baseline (501.483 us; speedup 1.0000x reference)
//
#include <hip/hip_runtime.h>
#include <hip/hip_bf16.h>
#include <hip/hip_cooperative_groups.h>

namespace cg = cooperative_groups;

#define NC 1000
#define FD 256
#define KPI 100    // labels per image (K)
#define CAP 1024   // bucket capacity per class (counts ~ Binom(200k, 1/1000) = 200 +/- 14)

// Single fused cooperative kernel: grid = NC blocks x 256 threads (4 waves).
// Phase 0: zero cursor + M (block 0/1)          -> grid.sync
// Phase 1: bucket scatter + presence bitmask    -> grid.sync
// Phase 2: per-class normalize+mean+EMA + cooc row
__global__ __launch_bounds__(256) void k_fused(
    const float* __restrict__ feat,
    const int* __restrict__ labels, int n,
    const int* __restrict__ lpi, int bk,
    const float* __restrict__ protos,
    const int* __restrict__ init_mask,
    const int* __restrict__ step,
    const float* __restrict__ cooc_in,
    int* __restrict__ cursor,
    unsigned long long* __restrict__ M,
    int* __restrict__ rowidx,
    float* __restrict__ out_protos,
    float* __restrict__ out_init,
    float* __restrict__ out_cooc) {
    cg::grid_group grid = cg::this_grid();
    int tid = threadIdx.x;
    int gid = blockIdx.x * 256 + tid;

    // ---- phase 0: zero the 12 KB of control state (block 0: cursor, block 1: M) ----
    if (blockIdx.x == 0) {
        for (int i = tid; i < NC; i += 256) cursor[i] = 0;
    } else if (blockIdx.x == 1) {
        for (int i = tid; i < NC; i += 256) M[i] = 0ull;
    }
    grid.sync();

    // ---- phase 1: direct bucket scatter + count + presence bitmask ----
    for (int i = gid; i < n; i += gridDim.x * 256) {
        int lab = labels[i];
        int pos = atomicAdd(&cursor[lab], 1);
        if (pos < CAP) rowidx[lab * CAP + pos] = i;
    }
    if (gid < bk) atomicOr(&M[lpi[gid]], 1ull << (gid / KPI));
    grid.sync();

    // ---- phase 2: per-class normalize+mean + prototype EMA + cooc row ----
    int c = blockIdx.x;
    int lane = tid & 63;
    int w = tid >> 6;
    int cnt = cursor[c];
    if (cnt > CAP) cnt = CAP;
    int start = c * CAP;
    int end = start + cnt;

    const float4* f4 = (const float4*)feat;
    float ax = 0.f, ay = 0.f, az = 0.f, aw = 0.f;

    // wave w handles rows [start+4w, start+4w+4), stride 16; 4 KB in flight per wave
    for (int base = start + 4 * w; base < end; base += 16) {
        int r[4];
        float4 v[4];
        float s[4];
        #pragma unroll
        for (int k = 0; k < 4; k++) {
            int idx = (base + k < end) ? (base + k) : (end - 1);  // loop entered => end > start
            r[k] = rowidx[idx];
        }
        #pragma unroll
        for (int k = 0; k < 4; k++) v[k] = f4[(size_t)r[k] * 64 + lane];
        #pragma unroll
        for (int k = 0; k < 4; k++)
            s[k] = v[k].x * v[k].x + v[k].y * v[k].y + v[k].z * v[k].z + v[k].w * v[k].w;
        #pragma unroll
        for (int o = 32; o; o >>= 1) {
            #pragma unroll
            for (int k = 0; k < 4; k++) s[k] += __shfl_xor(s[k], o);
        }
        #pragma unroll
        for (int k = 0; k < 4; k++) {
            float sc = (base + k < end) ? (1.0f / fmaxf(sqrtf(s[k]), 1e-12f)) : 0.0f;
            ax += v[k].x * sc;
            ay += v[k].y * sc;
            az += v[k].z * sc;
            aw += v[k].w * sc;
        }
    }

    // cross-wave combine: 4 waves x 64 lanes of float4 (= 4 x 256 floats)
    __shared__ float4 sh4[256];
    sh4[w * 64 + lane] = make_float4(ax, ay, az, aw);
    __syncthreads();

    const float* shf = (const float*)sh4;
    int d = tid;  // feature dim 0..255
    float t = shf[d] + shf[256 + d] + shf[512 + d] + shf[768 + d];
    float mean = t / fmaxf((float)cnt, 1.0f);

    float p = protos[c * FD + d];
    bool present = cnt > 0;
    bool inited = init_mask[c] > 0;
    float prog = fminf(1.0f, (float)step[0] / 2000.0f);   // WARMUP_STEPS*10
    float m = 0.99f + (0.999f - 0.99f) * prog;
    float ema = m * p + (1.0f - m) * mean;
    float outv = present ? (inited ? ema : mean) : p;
    out_protos[c * FD + d] = outv;
    if (tid == 0) out_init[c] = (inited || present) ? 1.0f : 0.0f;

    // cooc row c
    unsigned long long mi = M[c];
    for (int j = tid; j < NC; j += 256) {
        float add = (c == j) ? 0.0f : (float)__popcll(mi & M[j]);
        out_cooc[c * NC + j] = cooc_in[c * NC + j] + add;
    }
}

extern "C" void kernel_launch(void* const* d_in, const int* in_sizes, int n_in,
                              void* d_out, int out_size, void* d_ws, size_t ws_size,
                              hipStream_t stream) {
    const float* feat      = (const float*)d_in[0];
    const int*   labels    = (const int*)d_in[1];
    const int*   lpi       = (const int*)d_in[2];
    const float* protos    = (const float*)d_in[3];
    const int*   init_mask = (const int*)d_in[4];
    const float* cooc      = (const float*)d_in[5];
    const int*   step      = (const int*)d_in[6];

    int n  = in_sizes[1];   // 200000
    int bk = in_sizes[2];   // 6400

    float* out_protos = (float*)d_out;
    float* out_init   = out_protos + (size_t)NC * FD;
    float* out_cooc   = out_init + NC;

    // ws layout (bytes): [cursor 4096][M 8192][rowidx NC*CAP*4]
    char* ws = (char*)d_ws;
    int* cursor           = (int*)(ws);
    unsigned long long* M = (unsigned long long*)(ws + 4096);
    int* rowidx           = (int*)(ws + 12288);

    void* args[] = {
        (void*)&feat, (void*)&labels, (void*)&n, (void*)&lpi, (void*)&bk,
        (void*)&protos, (void*)&init_mask, (void*)&step, (void*)&cooc,
        (void*)&cursor, (void*)&M, (void*)&rowidx,
        (void*)&out_protos, (void*)&out_init, (void*)&out_cooc
    };
    hipLaunchCooperativeKernel(reinterpret_cast<void*>(k_fused),
                               dim3(NC), dim3(256), args, 0, stream);
}